// Round 7
// baseline (685.017 us; speedup 1.0000x reference)
//
#include <hip/hip_runtime.h>
#include <hip/hip_bf16.h>

// LSTM B=1024,T=512,F=64,H=128. R7: BB=2 rows/block, grid=512 -> 2 blocks/CU
// (4 waves/SIMD, two INDEPENDENT barrier groups that anti-phase: one block
// issues while the other sits in its serial chain / barrier stalls).
// CRITICAL: __launch_bounds__(512,2) — R5 proved (512,4)'s 128-reg cap spills
// the 96-VGPR weight array to scratch (9.8 GB HBM, 9x regression). Kernel is
// ~108 VGPR; 2 blocks co-reside because 4 waves/SIMD x 108 <= 512 VGPRs.
// With BB=2, A-row map h[(m>>2)&1] makes EVERY D reg = own batch row (q&1):
// no rotation, no select. x-GEMM batched 4 timesteps into M. Raw
// lgkmcnt-only barriers (x prefetch never drained). Bias pre-seeded in
// x-GEMM C operand. f32->bf16 via 2-op round-half-up. h_sm double-buffered,
// HPAD=144 (<=2-way LDS banks).

#define T_SEQ   512
#define F_IN    64
#define H_DIM   128
#define BB      2
#define NTHREADS 512
#define NG      4    // gate tiles per wave
#define KH      4    // h k-steps (K=128)
#define CH      4    // timestep chunk for batched x-GEMM
#define HPAD    144

typedef __bf16 bf16x8 __attribute__((ext_vector_type(8)));
typedef float  floatx4 __attribute__((ext_vector_type(4)));

__device__ __forceinline__ unsigned pk2_bf16(float a, float b) {
    unsigned ua = __builtin_bit_cast(unsigned, a);
    unsigned ub = __builtin_bit_cast(unsigned, b);
    return ((ua + 0x8000u) >> 16) | ((ub + 0x8000u) & 0xFFFF0000u);
}
__device__ __forceinline__ bf16x8 pack_frag(const float4 lo, const float4 hi) {
    union { unsigned u[4]; bf16x8 v; } r;
    r.u[0] = pk2_bf16(lo.x, lo.y);
    r.u[1] = pk2_bf16(lo.z, lo.w);
    r.u[2] = pk2_bf16(hi.x, hi.y);
    r.u[3] = pk2_bf16(hi.z, hi.w);
    return r.v;
}
__device__ __forceinline__ __bf16 bf16_rhu(float f) {
    unsigned u = __builtin_bit_cast(unsigned, f) + 0x8000u;
    unsigned short s = (unsigned short)(u >> 16);
    return __builtin_bit_cast(__bf16, s);
}
__device__ __forceinline__ __bf16 to_bf16(float f) {   // RNE, prologue only
    union { __hip_bfloat16 h; __bf16 b; } u;
    u.h = __float2bfloat16(f);
    return u.b;
}
__device__ __forceinline__ float fast_rcp(float x) { return __builtin_amdgcn_rcpf(x); }
__device__ __forceinline__ float sigmoid_f(float x) { return fast_rcp(1.0f + __expf(-x)); }
__device__ __forceinline__ float tanh_f(float x) {
    float e2 = __expf(2.0f * x);
    return (e2 - 1.0f) * fast_rcp(e2 + 1.0f);
}
// barrier with LDS visibility but NO vmcnt drain (x prefetch stays in flight)
__device__ __forceinline__ void lds_barrier() {
    asm volatile("s_waitcnt lgkmcnt(0)\n\ts_barrier" ::: "memory");
}

__global__ __launch_bounds__(NTHREADS, 2)
void lstm_fused_kernel(const float* __restrict__ x,
                       const float* __restrict__ W_ih,
                       const float* __restrict__ W_hh,
                       const float* __restrict__ b_ih,
                       const float* __restrict__ b_hh,
                       const float* __restrict__ W_out,
                       const float* __restrict__ b_out,
                       float* __restrict__ out)
{
    const int tid = threadIdx.x;
    const int w   = tid >> 6;
    const int l   = tid & 63;
    const int lm  = l & 15;        // A row within tile; B col-within-tile
    const int q   = l >> 4;        // quad: A k-sub; D row group
    const int b0  = blockIdx.x * BB;
    const int jcol = w * 16 + lm;  // hidden col this lane EWs
    const int qrow = q & 1;        // EW batch row

    __shared__ __align__(16) __bf16 h_sm[2][BB][HPAD];
    __shared__ float hf_sm[BB][H_DIM];

    // persistent weight B-frags: elem j = W[n][kb+j], n = g*128 + jcol,
    // kb = s*32 + q*8; s<4 -> W_hh, s>=4 -> W_ih(k-128). bias per gate.
    bf16x8 wf[NG][KH + 2];
    float  biasf[NG];
    #pragma unroll
    for (int g = 0; g < NG; ++g) {
        const int n = g * H_DIM + jcol;
        biasf[g] = b_ih[n] + b_hh[n];
        #pragma unroll
        for (int s = 0; s < KH + 2; ++s) {
            const int kb = s * 32 + q * 8;
            const float* src = (kb < 128) ? (W_hh + (size_t)n * 128 + kb)
                                          : (W_ih + (size_t)n * 64 + (kb - 128));
            const float4 f0 = *reinterpret_cast<const float4*>(src);
            const float4 f1 = *reinterpret_cast<const float4*>(src + 4);
            bf16x8 v;
            v[0] = to_bf16(f0.x); v[1] = to_bf16(f0.y);
            v[2] = to_bf16(f0.z); v[3] = to_bf16(f0.w);
            v[4] = to_bf16(f1.x); v[5] = to_bf16(f1.y);
            v[6] = to_bf16(f1.z); v[7] = to_bf16(f1.w);
            wf[g][s] = v;
        }
    }

    for (int idx = tid; idx < 2 * BB * HPAD; idx += NTHREADS)
        (&h_sm[0][0][0])[idx] = to_bf16(0.0f);

    // x-GEMM A source: A row m: br = (m>>2)&1, tsub = m&3. D row 4q+r ->
    // br = q&1 (all regs), tsub = r: lane q's reg r = xg[qrow][tc+r].
    const float* xga = x + ((size_t)(b0 + ((lm >> 2) & 1)) * T_SEQ + (lm & 3)) * F_IN + q * 8;

    // prologue: xg_cur = bias + xg(chunk 0); xld = x(chunk 1)
    floatx4 xg_cur[NG];
    {
        const float4 a0 = *reinterpret_cast<const float4*>(xga);
        const float4 a1 = *reinterpret_cast<const float4*>(xga + 4);
        const float4 a2 = *reinterpret_cast<const float4*>(xga + 32);
        const float4 a3 = *reinterpret_cast<const float4*>(xga + 36);
        const bf16x8 ax0 = pack_frag(a0, a1);
        const bf16x8 ax1 = pack_frag(a2, a3);
        #pragma unroll
        for (int g = 0; g < NG; ++g) {
            const floatx4 bias4 = {biasf[g], biasf[g], biasf[g], biasf[g]};
            xg_cur[g] = __builtin_amdgcn_mfma_f32_16x16x32_bf16(ax0, wf[g][KH + 0], bias4, 0, 0, 0);
            xg_cur[g] = __builtin_amdgcn_mfma_f32_16x16x32_bf16(ax1, wf[g][KH + 1], xg_cur[g], 0, 0, 0);
        }
    }
    float4 xld[4];
    {
        const float* xp = xga + CH * F_IN;
        xld[0] = *reinterpret_cast<const float4*>(xp);
        xld[1] = *reinterpret_cast<const float4*>(xp + 4);
        xld[2] = *reinterpret_cast<const float4*>(xp + 32);
        xld[3] = *reinterpret_cast<const float4*>(xp + 36);
    }

    float c = 0.0f, hval = 0.0f;
    const floatx4 zero4 = {0.f, 0.f, 0.f, 0.f};

    #pragma unroll 1
    for (int tc = 0; tc < T_SEQ; tc += CH) {
        floatx4 xg_next[NG];
        float4  xnew[4];
        #pragma unroll
        for (int r = 0; r < CH; ++r) {
            lds_barrier();   // h(tc+r-1) visible; x loads NOT drained

            if (r == 0) {
                // loads for chunk C+2 — consumed at next chunk's r==0 pack;
                // ~4 steps in flight (never drained by a barrier)
                const int tn = (tc + 2 * CH < T_SEQ) ? (tc + 2 * CH) : (T_SEQ - CH);
                const float* xp = xga + (size_t)tn * F_IN;
                xnew[0] = *reinterpret_cast<const float4*>(xp);
                xnew[1] = *reinterpret_cast<const float4*>(xp + 4);
                xnew[2] = *reinterpret_cast<const float4*>(xp + 32);
                xnew[3] = *reinterpret_cast<const float4*>(xp + 36);
                // xg_next = bias + xg(chunk C+1) from xld
                const bf16x8 ax0 = pack_frag(xld[0], xld[1]);
                const bf16x8 ax1 = pack_frag(xld[2], xld[3]);
                #pragma unroll
                for (int g = 0; g < NG; ++g) {
                    const floatx4 bias4 = {biasf[g], biasf[g], biasf[g], biasf[g]};
                    xg_next[g] = __builtin_amdgcn_mfma_f32_16x16x32_bf16(ax0, wf[g][KH + 0], bias4, 0, 0, 0);
                    xg_next[g] = __builtin_amdgcn_mfma_f32_16x16x32_bf16(ax1, wf[g][KH + 1], xg_next[g], 0, 0, 0);
                }
            }

            // h-GEMM: A row m reads h[(m>>2)&1] -> every D reg = own row q&1.
            // Two independent 2-deep MFMA chains.
            const int p = r & 1;
            const __bf16* hrow = &h_sm[p][(lm >> 2) & 1][q * 8];
            bf16x8 ah[KH];
            #pragma unroll
            for (int s = 0; s < KH; ++s)
                ah[s] = *reinterpret_cast<const bf16x8*>(hrow + s * 32);
            floatx4 hacc0[NG], hacc1[NG];
            #pragma unroll
            for (int g = 0; g < NG; ++g) {
                hacc0[g] = __builtin_amdgcn_mfma_f32_16x16x32_bf16(ah[0], wf[g][0], zero4, 0, 0, 0);
                hacc1[g] = __builtin_amdgcn_mfma_f32_16x16x32_bf16(ah[2], wf[g][2], zero4, 0, 0, 0);
            }
            #pragma unroll
            for (int g = 0; g < NG; ++g) {
                hacc0[g] = __builtin_amdgcn_mfma_f32_16x16x32_bf16(ah[1], wf[g][1], hacc0[g], 0, 0, 0);
                hacc1[g] = __builtin_amdgcn_mfma_f32_16x16x32_bf16(ah[3], wf[g][3], hacc1[g], 0, 0, 0);
            }

            // gate = own-row h contribution (reg 0) + (bias + xg)
            const float i_ = sigmoid_f(hacc0[0][0] + hacc1[0][0] + xg_cur[0][r]);
            const float f_ = sigmoid_f(hacc0[1][0] + hacc1[1][0] + xg_cur[1][r]);
            const float g_ = tanh_f   (hacc0[2][0] + hacc1[2][0] + xg_cur[2][r]);
            const float o_ = sigmoid_f(hacc0[3][0] + hacc1[3][0] + xg_cur[3][r]);
            c    = f_ * c + i_ * g_;
            hval = o_ * tanh_f(c);
            // replicas (q and q+2) write identical bits to the same address
            h_sm[p ^ 1][qrow][jcol] = bf16_rhu(hval);
        }
        #pragma unroll
        for (int g = 0; g < NG; ++g) xg_cur[g] = xg_next[g];
        #pragma unroll
        for (int i = 0; i < 4; ++i)  xld[i] = xnew[i];
    }

    // projection: out[b] = h_T @ W_out^T + b_out
    hf_sm[qrow][jcol] = hval;
    __syncthreads();
    if (tid < BB * H_DIM) {
        const int m = tid >> 7, n = tid & 127;
        float sum = b_out[n];
        const float* wrow = W_out + (size_t)n * H_DIM;
        #pragma unroll 8
        for (int jj = 0; jj < H_DIM; ++jj)
            sum += hf_sm[m][jj] * wrow[jj];
        out[(size_t)(b0 + m) * H_DIM + n] = sum;
    }
}

extern "C" void kernel_launch(void* const* d_in, const int* in_sizes, int n_in,
                              void* d_out, int out_size, void* d_ws, size_t ws_size,
                              hipStream_t stream) {
    const float* x     = (const float*)d_in[0];
    const float* W_ih  = (const float*)d_in[1];
    const float* W_hh  = (const float*)d_in[2];
    const float* b_ih  = (const float*)d_in[3];
    const float* b_hh  = (const float*)d_in[4];
    const float* W_out = (const float*)d_in[5];
    const float* b_out = (const float*)d_in[6];
    float* out = (float*)d_out;

    lstm_fused_kernel<<<dim3(1024 / BB), dim3(NTHREADS), 0, stream>>>(
        x, W_ih, W_hh, b_ih, b_hh, W_out, b_out, out);
}